// Round 13
// baseline (436.801 us; speedup 1.0000x reference)
//
#include <hip/hip_runtime.h>
#include <stdint.h>

// ---------------------------------------------------------------------------
// XlaQuantizedLinear: out[M,N] = (x[M,K] @ w[N,K]^T) * scaler[N]
// Round 13: i8 GEMM (round-12 memory schedule, byte-identical ledger) with
// INTRA-PHASE MFMA/ds_read INTERLEAVE. r12's serial model: per K-tile/CU
// measured 4967cy = MFMA 2612 + LDS 2304 (in series). Cause: program order
// [16 MFMA][reads] + WAR (reads overwrite the MFMA cluster's operand bank)
// -> compiler can't hoist reads without renaming. Fix: quarter-granularity
// interleave — MMAQ quarter f uses only a[2f..2f+1]; read new a[2f..2f+1]
// right after that quarter. Zero extra registers; LDS issue starts ~4 MFMAs
// into the cluster instead of after 16.
//  phi1: {MMAQ(1,1) qf; LDA2 a.qf}x4          | stage A0(t+1)   | VMW(4)
//  phi2: LDB4 b1 (no WAR: b1 dead); MMAQ(0,0) | stage B0(t+1)   | VMW(4)
//  phi3: {MMAQ(0,1) qf; LDA2 a.qf}x4          | stage B1(t+1)   | VMW(4)
//  phi4: {MMAQ(1,0) qnf; LDB2 b0.qnf}x2       | stage A1(t+1)   | VMW(2)
// vmcnt/WAR/ring ledger identical to r12 (reads stay in the same phases
// between the same barriers; stages unchanged).
// ---------------------------------------------------------------------------

typedef __attribute__((ext_vector_type(4))) int i32x4;      // i8 frag & acc
typedef __attribute__((ext_vector_type(4))) short short4v;
typedef __attribute__((ext_vector_type(4))) float f32x4;

#define NXCD 8
#define RSZ 16384
#define RING 81920

__device__ __forceinline__ short bf16_bits(float f) {
  uint32_t u = __builtin_bit_cast(uint32_t, f);
  uint32_t r = (u + 0x7FFFu + ((u >> 16) & 1u)) >> 16;
  return (short)r;
}

__device__ __forceinline__ void gl_lds16(const void* g, void* l) {
  __builtin_amdgcn_global_load_lds(
      (const __attribute__((address_space(1))) void*)g,
      (__attribute__((address_space(3))) void*)l, 16, 0, 0);
}

__global__ __launch_bounds__(512, 2) void gemm256i8(
    const char* __restrict__ A, const char* __restrict__ B,
    const float* __restrict__ rs, const float* __restrict__ scaler,
    float* __restrict__ C, int M, int N, int K) {
  __shared__ alignas(16) char sm[RING];  // 80 KB

  const int tid = threadIdx.x;
  const int l = tid & 63;
  const int w = tid >> 6;
  const int wr = w >> 2, wc = w & 3;
  const int ln15 = l & 15;

  // bijective XCD-aware swizzle (m204)
  const int nwg = gridDim.x;
  const int ntn = N >> 8;
  int bid = blockIdx.x;
  int q = nwg / NXCD, rr = nwg % NXCD;
  int xcd = bid % NXCD, idx = bid / NXCD;
  int swz = (xcd < rr ? xcd * (q + 1) : rr * (q + 1) + (xcd - rr) * q) + idx;
  const int m0 = (swz / ntn) << 8, n0 = (swz % ntn) << 8;

  const size_t ldkb = (size_t)K;   // bytes per row (i8)

  // staging per-thread bases (source pre-swizzled: rule 21)
  const int srow8 = l >> 3;
  const int sswz = ((l & 7) ^ srow8) << 4;
  const char* Ag = A + (size_t)(m0 + w * 8 + srow8) * ldkb + sswz;
  const char* Bg = B + (size_t)(n0 + (w >> 2) * 64 + (w & 3) * 8 + srow8) * ldkb + sswz;

  // read-side swizzled k offsets
  const int swzc = (l & 7) << 4;
  const int klo = (l >> 4) << 4;
  const int e45 = klo ^ (swzc & 48);
  const int s6 = swzc & 64;
  const int kof0 = e45 | s6;
  const int kof1 = e45 | (64 ^ s6);

  i32x4 acc[8][4] = {};
  i32x4 a[8], b0[4], b1[4];

  const int NT = K >> 7;            // K-tiles of 128 (>=3)

#define WRAP(x) ((x) >= RING ? (x) - RING : (x))

// quarter read: new a[2f],a[2f+1]
#define LDA2R(base, dst, f) do {                                              \
    const char* _b = sm + (base) + (wr * 64 + ln15) * 128 + (f) * 2048;       \
    dst[(f)*2+0] = *(const i32x4*)(_b + kof0);                                \
    dst[(f)*2+1] = *(const i32x4*)(_b + kof1); } while (0)

#define LDB2R(base, dst, nf) do {                                             \
    const char* _b = sm + (base) + (wc * 32 + ln15) * 128 + (nf) * 2048;      \
    dst[(nf)*2+0] = *(const i32x4*)(_b + kof0);                               \
    dst[(nf)*2+1] = *(const i32x4*)(_b + kof1); } while (0)

#define LDA8R(base, dst) do {                                                 \
    _Pragma("unroll") for (int f = 0; f < 4; ++f) LDA2R(base, dst, f);        \
  } while (0)

#define LDB4R(base, dst) do {                                                 \
    _Pragma("unroll") for (int nf = 0; nf < 2; ++nf) LDB2R(base, dst, nf);    \
  } while (0)

#define STAGE_A(base, mh, tb) do {                                            \
    gl_lds16(Ag + (size_t)((mh)*64) * ldkb + (tb),                            \
             sm + (base) + w * 1024);                                         \
    gl_lds16(Ag + (size_t)((mh)*64 + 128) * ldkb + (tb),                      \
             sm + (base) + 8192 + w * 1024); } while (0)

#define STAGE_B(base, nh, tb) do {                                            \
    gl_lds16(Bg + (size_t)((nh)*32) * ldkb + (tb),                            \
             sm + (base) + w * 1024);                                         \
    gl_lds16(Bg + (size_t)((nh)*32 + 128) * ldkb + (tb),                      \
             sm + (base) + 8192 + w * 1024); } while (0)

// 4 MFMAs of quarter f (fixed f; nf,ks loops)
#define MMAQ_F(mh, nh, f, av, bv) do {                                        \
    _Pragma("unroll") for (int nf = 0; nf < 2; ++nf)                          \
    _Pragma("unroll") for (int ks = 0; ks < 2; ++ks)                          \
      acc[(mh)*4+(f)][(nh)*2+nf] = __builtin_amdgcn_mfma_i32_16x16x64_i8(     \
          av[(f)*2+ks], bv[nf*2+ks], acc[(mh)*4+(f)][(nh)*2+nf], 0, 0, 0);    \
  } while (0)

// 8 MFMAs of b-quarter nf (fixed nf; f,ks loops)
#define MMAQ_NF(mh, nh, nf, av, bv) do {                                      \
    _Pragma("unroll") for (int f = 0; f < 4; ++f)                             \
    _Pragma("unroll") for (int ks = 0; ks < 2; ++ks)                          \
      acc[(mh)*4+f][(nh)*2+(nf)] = __builtin_amdgcn_mfma_i32_16x16x64_i8(     \
          av[f*2+ks], bv[(nf)*2+ks], acc[(mh)*4+f][(nh)*2+(nf)], 0, 0, 0);    \
  } while (0)

#define MMAQ(mh, nh, av, bv) do {                                             \
    _Pragma("unroll") for (int f = 0; f < 4; ++f) MMAQ_F(mh, nh, f, av, bv);  \
  } while (0)

// interleaved: MMAQ(mh,nh) on av + refill av from region base
#define MMAQ_ILVA(mh, nh, av, bv, base) do {                                  \
    MMAQ_F(mh, nh, 0, av, bv); LDA2R(base, av, 0);                            \
    MMAQ_F(mh, nh, 1, av, bv); LDA2R(base, av, 1);                            \
    MMAQ_F(mh, nh, 2, av, bv); LDA2R(base, av, 2);                            \
    MMAQ_F(mh, nh, 3, av, bv); LDA2R(base, av, 3); } while (0)

// interleaved: MMAQ(mh,nh) on bv + refill bv from region base
#define MMAQ_ILVB(mh, nh, av, bv, base) do {                                  \
    MMAQ_NF(mh, nh, 0, av, bv); LDB2R(base, bv, 0);                           \
    MMAQ_NF(mh, nh, 1, av, bv); LDB2R(base, bv, 1); } while (0)

#define BAR() do { __builtin_amdgcn_sched_barrier(0);                         \
    asm volatile("s_barrier" ::: "memory");                                   \
    __builtin_amdgcn_sched_barrier(0); } while (0)

#define VMW(n) asm volatile("s_waitcnt vmcnt(" #n ")" ::: "memory")

  // prologue: stage tile0 (A0@0,B0@1,B1@2,A1@3); retire; publish
  STAGE_A(0 * RSZ, 0, 0);
  STAGE_B(1 * RSZ, 0, 0);
  STAGE_B(2 * RSZ, 1, 0);
  STAGE_A(3 * RSZ, 1, 0);
  VMW(4);
  BAR();

  // ---- t = 0 peel ----
  {
    const size_t tb1 = 128;  // tile 1 byte offset
    // "phi4(-1)" read + phi1(0): no carry MMAQ
    LDB4R(1 * RSZ, b0);            // B0(0)
    LDA8R(0 * RSZ, a);             // A0(0)
    STAGE_A(4 * RSZ, 0, tb1);      // A0(1) -> region 4
    // phi2(0)
    VMW(4); BAR();                 // retires B1(0)
    LDB4R(2 * RSZ, b1);            // B1(0)  (no WAR with MMAQ(0,0))
    MMAQ(0, 0, a, b0);
    STAGE_B(0 * RSZ, 0, tb1);      // B0(1) -> region 0
    // phi3(0)
    VMW(4); BAR();                 // retires A1(0)
    MMAQ_ILVA(0, 1, a, b1, 3 * RSZ);   // MFMA on A0, refill a <- A1(0)
    STAGE_B(1 * RSZ, 1, tb1);      // B1(1) -> region 1
    // phi4(0)
    VMW(2); BAR();                 // retires A0(1),B0(1)
    MMAQ_ILVB(1, 0, a, b0, 0 * RSZ);   // MFMA on B0(0), refill b0 <- B0(1)
    STAGE_A(2 * RSZ, 1, tb1);      // A1(1) -> region 2
  }

  int rb = 4 * RSZ;  // tile1's A0 region

  // ---- main tiles t = 1 .. NT-2 ----
  for (int t = 1; t < NT - 1; ++t) {
    const int rA0 = rb, rB0 = WRAP(rb + RSZ), rB1 = WRAP(rb + 2 * RSZ);
    const int rA1 = WRAP(rb + 3 * RSZ), rN = WRAP(rb + 4 * RSZ);
    const size_t tbn = (size_t)(t + 1) << 7;
    // phi1: carry MMAQ(1,1) on a=A1(t-1); refill a <- A0(t)
    VMW(4); BAR();
    MMAQ_ILVA(1, 1, a, b1, rA0);
    STAGE_A(rN, 0, tbn);
    // phi2: reads first (b1 dead since phi1)
    VMW(4); BAR();                 // retires B1(t)
    LDB4R(rB1, b1);
    MMAQ(0, 0, a, b0);
    STAGE_B(rA0, 0, tbn);          // B0(t+1) -> rA0
    // phi3: MMAQ(0,1) on a=A0(t); refill a <- A1(t)
    VMW(4); BAR();                 // retires A1(t)
    MMAQ_ILVA(0, 1, a, b1, rA1);
    STAGE_B(rB0, 1, tbn);
    // phi4: MMAQ(1,0) on b0=B0(t); refill b0 <- B0(t+1)
    VMW(2); BAR();                 // retires A0(t+1),B0(t+1)
    MMAQ_ILVB(1, 0, a, b0, rA0);
    STAGE_A(rB1, 1, tbn);
    rb = rN;
  }

  // ---- tail t = NT-1 (no stages; draining) ----
  {
    const int rA0 = rb, rB1 = WRAP(rb + 2 * RSZ), rA1 = WRAP(rb + 3 * RSZ);
    // phi1
    VMW(4); BAR();
    MMAQ_ILVA(1, 1, a, b1, rA0);
    // phi2
    VMW(2); BAR();                 // retires B1(NT-1)
    LDB4R(rB1, b1);
    MMAQ(0, 0, a, b0);
    // phi3
    VMW(0); BAR();                 // retires A1(NT-1)
    MMAQ_ILVA(0, 1, a, b1, rA1);
    // phi4
    BAR();
    MMAQ(1, 0, a, b0);
  }
  MMAQ(1, 1, a, b1);               // final carry-out

  // epilogue: out = acc * rs[row] * scaler[col]
  float scl[4];
#pragma unroll
  for (int ng = 0; ng < 4; ++ng)
    scl[ng] = scaler[n0 + wc * 64 + (ng >> 1) * 32 + (ng & 1) * 16 + ln15];
  const int row0 = m0 + wr * 128 + ((l >> 4) << 2);
  const int col0 = n0 + wc * 64 + ln15;
#pragma unroll
  for (int mf = 0; mf < 8; ++mf) {
    const int rbase = row0 + (mf >> 2) * 64 + (mf & 3) * 16;
#pragma unroll
    for (int j = 0; j < 4; ++j) {
      const float dr = rs[rbase + j];
      float* cp = C + (size_t)(rbase + j) * N + col0;
#pragma unroll
      for (int ng = 0; ng < 4; ++ng)
        cp[(ng >> 1) * 32 + (ng & 1) * 16] =
            (float)acc[mf][ng][j] * dr * scl[ng];
    }
  }
#undef WRAP
#undef LDA2R
#undef LDB2R
#undef LDA8R
#undef LDB4R
#undef STAGE_A
#undef STAGE_B
#undef MMAQ_F
#undef MMAQ_NF
#undef MMAQ
#undef MMAQ_ILVA
#undef MMAQ_ILVB
#undef BAR
#undef VMW
}

// ---- x per-row quantize, K==4096 fast path: row held in 16 VGPRs ----------
__global__ __launch_bounds__(256) void qrow4k(const float* __restrict__ x,
                                              char* __restrict__ q,
                                              float* __restrict__ rs) {
  const int r = blockIdx.x;
  const float4* xr = (const float4*)(x + (size_t)r * 4096);
  const int tid = threadIdx.x;
  float4 v[4];
  float mx = 0.f;
#pragma unroll
  for (int i = 0; i < 4; ++i) {
    v[i] = xr[tid + 256 * i];
    mx = fmaxf(mx, fmaxf(fmaxf(fabsf(v[i].x), fabsf(v[i].y)),
                         fmaxf(fabsf(v[i].z), fabsf(v[i].w))));
  }
#pragma unroll
  for (int off = 32; off; off >>= 1) mx = fmaxf(mx, __shfl_down(mx, off));
  __shared__ float smx[4];
  __shared__ float sinv;
  if ((tid & 63) == 0) smx[tid >> 6] = mx;
  __syncthreads();
  if (tid == 0) {
    float m = fmaxf(fmaxf(smx[0], smx[1]), fmaxf(smx[2], smx[3]));
    rs[r] = m / 127.0f;
    sinv = (m > 0.f) ? 127.0f / m : 0.f;
  }
  __syncthreads();
  const float inv = sinv;
  uint32_t* qr = (uint32_t*)(q + (size_t)r * 4096);
#pragma unroll
  for (int i = 0; i < 4; ++i) {
    int a0 = (int)rintf(v[i].x * inv), a1 = (int)rintf(v[i].y * inv);
    int a2 = (int)rintf(v[i].z * inv), a3 = (int)rintf(v[i].w * inv);
    qr[tid + 256 * i] =
        (uint32_t)(a0 & 0xff) | ((uint32_t)(a1 & 0xff) << 8) |
        ((uint32_t)(a2 & 0xff) << 16) | ((uint32_t)(a3 & 0xff) << 24);
  }
}

// ---- general per-row quantize (2-pass), any K%4==0 -------------------------
__global__ __launch_bounds__(256) void qrow(const float* __restrict__ x,
                                            char* __restrict__ q,
                                            float* __restrict__ rs, int K) {
  const int r = blockIdx.x;
  const float* xr = x + (size_t)r * K;
  const int tid = threadIdx.x;
  const int n4 = K >> 2;
  float mx = 0.f;
  for (int i = tid; i < n4; i += 256) {
    float4 v = ((const float4*)xr)[i];
    mx = fmaxf(mx, fmaxf(fmaxf(fabsf(v.x), fabsf(v.y)),
                         fmaxf(fabsf(v.z), fabsf(v.w))));
  }
#pragma unroll
  for (int off = 32; off; off >>= 1) mx = fmaxf(mx, __shfl_down(mx, off));
  __shared__ float smx[4];
  __shared__ float sinv;
  if ((tid & 63) == 0) smx[tid >> 6] = mx;
  __syncthreads();
  if (tid == 0) {
    float m = fmaxf(fmaxf(smx[0], smx[1]), fmaxf(smx[2], smx[3]));
    rs[r] = m / 127.0f;
    sinv = (m > 0.f) ? 127.0f / m : 0.f;
  }
  __syncthreads();
  const float inv = sinv;
  uint32_t* qr = (uint32_t*)(q + (size_t)r * K);
  for (int i = tid; i < n4; i += 256) {
    float4 v = ((const float4*)xr)[i];
    int a0 = (int)rintf(v.x * inv), a1 = (int)rintf(v.y * inv);
    int a2 = (int)rintf(v.z * inv), a3 = (int)rintf(v.w * inv);
    qr[i] = (uint32_t)(a0 & 0xff) | ((uint32_t)(a1 & 0xff) << 8) |
            ((uint32_t)(a2 & 0xff) << 16) | ((uint32_t)(a3 & 0xff) << 24);
  }
}

// ---- w pack: int32 (0..126) -> i8, 16 per thread ---------------------------
__global__ void qw_pack(const int* __restrict__ wq, char* __restrict__ q,
                        long long n16) {
  long long i = (long long)blockIdx.x * blockDim.x + threadIdx.x;
  const long long stride = (long long)gridDim.x * blockDim.x;
  for (; i < n16; i += stride) {
    const int4* p = (const int4*)(wq + i * 16);
    uint32_t o[4];
#pragma unroll
    for (int k = 0; k < 4; ++k) {
      int4 v = p[k];
      o[k] = (uint32_t)(v.x & 0xff) | ((uint32_t)(v.y & 0xff) << 8) |
             ((uint32_t)(v.z & 0xff) << 16) | ((uint32_t)(v.w & 0xff) << 24);
    }
    uint4 pk = {o[0], o[1], o[2], o[3]};
    *(uint4*)(q + i * 16) = pk;
  }
}

// ---------------- fallback (no workspace needed, any shape) -----------------
#define FBM 128
#define FBN 128
#define FBK 32

__global__ __launch_bounds__(256) void gemm_fb(
    const float* __restrict__ A, const int* __restrict__ B,
    const float* __restrict__ scaler, float* __restrict__ C,
    int M, int N, int K) {
  __shared__ alignas(16) short As[FBM * FBK];
  __shared__ alignas(16) short Bs[FBN * FBK];

  const int tid = threadIdx.x;
  const int lane = tid & 63;
  const int wid = tid >> 6;
  const int wr = wid >> 1, wc = wid & 1;

  const int nwg = gridDim.x;
  const int ntn = N / FBN;
  int bid = blockIdx.x;
  int q = nwg / NXCD, r = nwg % NXCD;
  int xcd = bid % NXCD, idx = bid / NXCD;
  int swz = (xcd < r ? xcd * (q + 1) : r * (q + 1) + (xcd - r) * q) + idx;
  const int mt = swz / ntn, nt = swz % ntn;
  const int m0 = mt * FBM, n0 = nt * FBN;

  f32x4 acc[4][4] = {};
  const int kiters = K / FBK;

  for (int kt = 0; kt < kiters; ++kt) {
    const int k0 = kt * FBK;
    __syncthreads();
#pragma unroll
    for (int qq = 0; qq < 4; ++qq) {
      int chunk = qq * 256 + tid;
      int row = chunk >> 3;
      int c4 = (chunk & 7) * 4;
      float4 va = *(const float4*)&A[(size_t)(m0 + row) * K + k0 + c4];
      int4 vb = *(const int4*)&B[(size_t)(n0 + row) * K + k0 + c4];
      short4v wa, wb;
      wa[0] = bf16_bits(va.x); wa[1] = bf16_bits(va.y);
      wa[2] = bf16_bits(va.z); wa[3] = bf16_bits(va.w);
      wb[0] = bf16_bits((float)vb.x); wb[1] = bf16_bits((float)vb.y);
      wb[2] = bf16_bits((float)vb.z); wb[3] = bf16_bits((float)vb.w);
      *(short4v*)&As[row * FBK + c4] = wa;
      *(short4v*)&Bs[row * FBK + c4] = wb;
    }
    __syncthreads();
    const int ar = wr * 64 + (lane & 15);
    const int br = wc * 64 + (lane & 15);
    const int ko = (lane >> 4) * 8;
    typedef __attribute__((ext_vector_type(8))) short short8v;
    short8v av[4], bv[4];
#pragma unroll
    for (int i = 0; i < 4; ++i) {
      av[i] = *(const short8v*)&As[(ar + i * 16) * FBK + ko];
      bv[i] = *(const short8v*)&Bs[(br + i * 16) * FBK + ko];
    }
#pragma unroll
    for (int mi = 0; mi < 4; ++mi)
#pragma unroll
      for (int ni = 0; ni < 4; ++ni)
        acc[mi][ni] = __builtin_amdgcn_mfma_f32_16x16x32_bf16(
            av[mi], bv[ni], acc[mi][ni], 0, 0, 0);
  }

  float sc[4];
  const int cc0 = n0 + wc * 64 + (lane & 15);
#pragma unroll
  for (int ni = 0; ni < 4; ++ni) sc[ni] = scaler[cc0 + ni * 16];
  const int cr0 = m0 + wr * 64 + ((lane >> 4) << 2);
#pragma unroll
  for (int mi = 0; mi < 4; ++mi)
#pragma unroll
    for (int j = 0; j < 4; ++j) {
      float* crow = C + (size_t)(cr0 + mi * 16 + j) * N;
#pragma unroll
      for (int ni = 0; ni < 4; ++ni)
        crow[cc0 + ni * 16] = acc[mi][ni][j] * sc[ni];
    }
}

extern "C" void kernel_launch(void* const* d_in, const int* in_sizes, int n_in,
                              void* d_out, int out_size, void* d_ws,
                              size_t ws_size, hipStream_t stream) {
  const float* x = (const float*)d_in[0];       // [M][K] fp32
  const int* w = (const int*)d_in[1];           // [N][K] int32 (0..126)
  const float* sc = (const float*)d_in[2];      // [N] fp32
  float* out = (float*)d_out;                   // [M][N] fp32

  const long long xn = in_sizes[0];             // M*K
  const long long wn = in_sizes[1];             // N*K
  const int N = in_sizes[2];
  const int K = (int)(wn / N);
  const int M = (int)(xn / K);

  const size_t need = (size_t)xn + (size_t)wn + (size_t)M * 4;
  const bool okt = (M % 256 == 0) && (N % 256 == 0) && (K % 128 == 0) &&
                   (K >= 384) && (K % 4 == 0);

  if (ws_size >= need && okt) {
    char* xq = (char*)d_ws;                     // i8 x  [M][K]
    char* wq = xq + xn;                         // i8 w  [N][K]
    float* rs = (float*)(wq + wn);              // row scales [M]
    if (K == 4096)
      qrow4k<<<M, 256, 0, stream>>>(x, xq, rs);
    else
      qrow<<<M, 256, 0, stream>>>(x, xq, rs, K);
    qw_pack<<<2048, 256, 0, stream>>>(w, wq, wn / 16);
    const int grid = (M / 256) * (N / 256);
    gemm256i8<<<grid, 512, 0, stream>>>(xq, wq, rs, sc, out, M, N, K);
  } else {
    const int grid = (M / FBM) * (N / FBN);
    gemm_fb<<<grid, 256, 0, stream>>>(x, w, sc, out, M, N, K);
  }
}